// Round 3
// baseline (561.586 us; speedup 1.0000x reference)
//
#include <hip/hip_runtime.h>
#include <math.h>

#define NT 512

typedef __attribute__((ext_vector_type(8))) short s16x8;
typedef __attribute__((ext_vector_type(4))) short s16x4;
typedef __attribute__((ext_vector_type(4))) float f32x4;

// d_ws layout (bytes)
#define WKT_OFF 0        // bf16 K-weight B-frags: [nt8][kk4][512]  -> 32768 B
#define WVT_OFF 32768    // bf16 V-weight A-frags: [mt8][kk4][512]  -> 32768 B
#define WQT_OFF 65536    // bf16 Q-weight B-frags: [nt9][kk4][512]  -> 36864 B (SCALE folded)
#define PJF_OFF 102400   // bf16 proj A-frags: [h6][ct8][512] K=32  -> 49152 B
#define RPB_OFF 151552   // fp32 rpb^T: [h][tok192][q64]            -> 294912 B

__device__ __forceinline__ unsigned short f2bf(float f) {
    union { float f; unsigned int i; } v; v.f = f;
    unsigned int x = v.i;
    x += 0x7fffu + ((x >> 16) & 1u);   // round-nearest-even
    return (unsigned short)(x >> 16);
}
__device__ __forceinline__ unsigned int pk2(float a, float b) {
    return (unsigned int)f2bf(a) | ((unsigned int)f2bf(b) << 16);
}

#define MFMA(a, b, c) __builtin_amdgcn_mfma_f32_16x16x32_bf16(a, b, c, 0, 0, 0)

// ---------------- prep: weights -> bf16 fragments, rpb gathered+transposed ----------------
__global__ void prep(const float* __restrict__ qkv_w,
                     const float* __restrict__ proj_w,
                     const float* __restrict__ rpb_table,
                     const int*   __restrict__ rel_idx,
                     unsigned char* __restrict__ wsb)
{
    int gid = blockIdx.x * blockDim.x + threadIdx.x;
    int nthr = gridDim.x * blockDim.x;
    unsigned short* WKT = (unsigned short*)(wsb + WKT_OFF);
    unsigned short* WVT = (unsigned short*)(wsb + WVT_OFF);
    unsigned short* WQT = (unsigned short*)(wsb + WQT_OFF);
    unsigned short* PJF = (unsigned short*)(wsb + PJF_OFF);
    float*          RPB = (float*)(wsb + RPB_OFF);

    // K weights as B-frags, dense out cols: f = (nt*4+kk)*512 + ln*8 + j
    for (int f = gid; f < 8 * 4 * 512; f += nthr) {
        int q = f & 511, rest = f >> 9;
        int kk = rest & 3, nt = rest >> 2;
        int ln = q >> 3, j = q & 7, l15 = ln & 15, qd = ln >> 4;
        int c = nt * 16 + l15, ch = kk * 32 + qd * 8 + j;
        float v = (c < 120 && ch < 120) ? qkv_w[(120 + c) * 120 + ch] : 0.f;
        WKT[f] = f2bf(v);
    }
    // V weights as A-frags (for V^T = Wv * xw^T): f = (mt*4+kk)*512 + ln*8 + j
    for (int f = gid; f < 8 * 4 * 512; f += nthr) {
        int q = f & 511, rest = f >> 9;
        int kk = rest & 3, mt = rest >> 2;
        int ln = q >> 3, j = q & 7, l15 = ln & 15, qd = ln >> 4;
        int d = mt * 16 + l15, ch = kk * 32 + qd * 8 + j;
        float v = (d < 120 && ch < 120) ? qkv_w[(240 + d) * 120 + ch] : 0.f;
        WVT[f] = f2bf(v);
    }
    // Q weights as B-frags, out cols = [h6][24] padded (slots>=20 zero), SCALE folded
    for (int f = gid; f < 9 * 4 * 512; f += nthr) {
        int q = f & 511, rest = f >> 9;
        int kk = rest & 3, nt = rest >> 2;
        int ln = q >> 3, j = q & 7, l15 = ln & 15, qd = ln >> 4;
        int c = nt * 16 + l15, ch = kk * 32 + qd * 8 + j;      // c in 0..143
        int hh = (c * 171) >> 12, rel = c - hh * 24;
        float v = (rel < 20 && ch < 120)
                    ? qkv_w[(hh * 20 + rel) * 120 + ch] * 0.22360679774997896f : 0.f;
        WQT[f] = f2bf(v);
    }
    // proj fragments, per-head K=32 slice (k>=20 zero): f = (h*8+ct)*512 + ln*8 + j
    for (int f = gid; f < 6 * 8 * 512; f += nthr) {
        int q = f & 511, rest = f >> 9;
        int ct = rest & 7, h = rest >> 3;
        int ln = q >> 3, j = q & 7, l15 = ln & 15, qd = ln >> 4;
        int c = ct * 16 + l15, k = qd * 8 + j;
        float v = (k < 20 && c < 120) ? proj_w[c * 120 + h * 20 + k] : 0.f;
        PJF[f] = f2bf(v);
    }
    // rpb transposed: [h][tok(192)][q(64)] fp32
    for (int i = gid; i < 6 * 192 * 64; i += nthr) {
        int r = i & 63, n = (i >> 6) % 192, h = i / (192 * 64);
        RPB[i] = rpb_table[rel_idx[r * 192 + n] * 6 + h];
    }
}

// ---------------- main fused kernel: all-heads QKV once, barrier-free attention ----------------
__global__ __launch_bounds__(NT, 2)
void swin_mfma(const float* __restrict__ x,
               const float* __restrict__ quary0,
               const float* __restrict__ quary1,
               const float* __restrict__ qkv_b,
               const float* __restrict__ proj_b,
               const float* __restrict__ pm_w,
               const float* __restrict__ pm_b,
               const unsigned char* __restrict__ wsb,
               float* __restrict__ out)
{
    // 159,152 B -> 1 block/CU (8 waves)
    __shared__ alignas(16) unsigned char smem[159152];
    unsigned short* xw = (unsigned short*)smem;             // [192][120] + 8 pad   (46096 B)
    unsigned short* kd = (unsigned short*)(smem + 46096);   // K dense [192][120]+16 (46112 B)
    unsigned short* vt = (unsigned short*)(smem + 92208);   // V^T [120][200]        (48000 B)
    unsigned short* qp = (unsigned short*)(smem + 140208);  // Qpad [64][6*24]       (18432 B)
    float* pred_s = (float*)(smem + 158640);                // 64 floats
    int*   grp_s  = (int*)(smem + 158896);                  // 64 ints

    const int tid = threadIdx.x;
    const int wv = tid >> 6, ln = tid & 63;
    const int l15 = ln & 15, qd = ln >> 4;
    const int widx = blockIdx.x;
    const int wh = widx >> 5, ww = widx & 31;

    const unsigned short* WKT = (const unsigned short*)(wsb + WKT_OFF);
    const unsigned short* WVT = (const unsigned short*)(wsb + WVT_OFF);
    const unsigned short* WQT = (const unsigned short*)(wsb + WQT_OFF);
    const unsigned short* PJF = (const unsigned short*)(wsb + PJF_OFF);
    const float*          RPB = (const float*)(wsb + RPB_OFF);

    // ---------------- staging ----------------
    for (int e = tid; e < 192 * 30; e += NT) {
        int n = e / 30, c4 = e % 30;
        int f = n >> 6, ii = (n >> 3) & 7, jj = n & 7;
        int y0 = (wh * 8 + ii + 4) & 255;
        int x0 = (ww * 8 + jj + 4) & 255;
        float4 val = *(const float4*)(x + (((size_t)(f * 256 + y0)) * 256 + x0) * 120 + c4 * 4);
        unsigned int lo = (unsigned)f2bf(val.x) | ((unsigned)f2bf(val.y) << 16);
        unsigned int hi = (unsigned)f2bf(val.z) | ((unsigned)f2bf(val.w) << 16);
        unsigned int off = (unsigned)(n * 120 + c4 * 4);
        *(unsigned int*)(xw + off)     = lo;
        *(unsigned int*)(xw + off + 2) = hi;
    }
    if (tid < 8)  xw[192 * 120 + tid] = 0;
    if (tid < 16) kd[192 * 120 + tid] = 0;                  // K row-191 overflow pad
    if (tid < 64) {                                          // shift-mask region ids
        int ii = tid >> 3, jj = tid & 7;
        int y0 = (wh * 8 + ii + 4) & 255;
        int x0 = (ww * 8 + jj + 4) & 255;
        int hg = (y0 >= 248) + (y0 >= 252);
        int wg = (x0 >= 248) + (x0 >= 252);
        grp_s[tid] = hg * 3 + wg;
    }
    if (tid < 256) {                                         // pred in exact fp32
        int r = tid >> 2, j = tid & 3;
        int ii = r >> 3, jj = r & 7;
        int y0 = (wh * 8 + ii + 4) & 255;
        int x0 = (ww * 8 + jj + 4) & 255;
        const float* xr  = x + (((size_t)(2 * 256 + y0)) * 256 + x0) * 120;
        const float* q0r = quary0 + ((size_t)widx * 64 + r) * 120;
        float acc = 0.f;
        for (int ch = j * 30; ch < j * 30 + 30; ++ch)
            acc += fabsf(xr[ch] - q0r[ch]) * pm_w[ch];
        acc += __shfl_xor(acc, 1);
        acc += __shfl_xor(acc, 2);
        if (j == 0) pred_s[r] = (acc + pm_b[0] >= 0.f) ? 1.f : 0.f;
    }
    __syncthreads();

    // ---------------- all-heads QKV (one pass, 8 waves) ----------------
    // K = xw * Wk^T  (dense out, 48 pair-jobs)
    for (int e = wv; e < 48; e += 8) {
        int mt = e >> 2, ntp = e & 3;
        const unsigned short* arow = xw + (mt * 16 + l15) * 120;
        const unsigned short* b0 = WKT + (2 * ntp) * 4 * 512 + ln * 8;
        f32x4 a0 = {0.f,0.f,0.f,0.f}, a1 = {0.f,0.f,0.f,0.f};
        #pragma unroll
        for (int kk = 0; kk < 4; ++kk) {
            s16x8 aF = *(const s16x8*)(arow + kk * 32 + qd * 8);
            a0 = MFMA(aF, *(const s16x8*)(b0 + kk * 512), a0);
            a1 = MFMA(aF, *(const s16x8*)(b0 + 2048 + kk * 512), a1);
        }
        #pragma unroll
        for (int half = 0; half < 2; ++half) {
            int c = (2 * ntp + half) * 16 + l15;
            f32x4 acc = half ? a1 : a0;
            if (c < 120) {
                float bias = qkv_b[120 + c];
                #pragma unroll
                for (int reg = 0; reg < 4; ++reg)
                    kd[(mt * 16 + qd * 4 + reg) * 120 + c] = f2bf(acc[reg] + bias);
            }
        }
    }
    // V^T = Wv * xw^T  (48 pair-jobs; xw row-read doubles as B-frag)
    for (int e = wv; e < 48; e += 8) {
        int nt = e >> 2, mtp = e & 3;
        const unsigned short* brow = xw + (nt * 16 + l15) * 120;
        const unsigned short* a0 = WVT + (2 * mtp) * 4 * 512 + ln * 8;
        f32x4 c0 = {0.f,0.f,0.f,0.f}, c1 = {0.f,0.f,0.f,0.f};
        #pragma unroll
        for (int kk = 0; kk < 4; ++kk) {
            s16x8 bF = *(const s16x8*)(brow + kk * 32 + qd * 8);
            c0 = MFMA(*(const s16x8*)(a0 + kk * 512), bF, c0);
            c1 = MFMA(*(const s16x8*)(a0 + 2048 + kk * 512), bF, c1);
        }
        #pragma unroll
        for (int half = 0; half < 2; ++half) {
            f32x4 acc = half ? c1 : c0;
            #pragma unroll
            for (int reg = 0; reg < 4; ++reg) {
                int d = (2 * mtp + half) * 16 + qd * 4 + reg;
                if (d < 120)
                    vt[d * 200 + nt * 16 + l15] = f2bf(acc[reg] + qkv_b[240 + d]);
            }
        }
    }
    // Q = xw_q * Wq^T  (padded [6][24] out cols, zeros auto-written; 36 jobs)
    for (int e = wv; e < 36; e += 8) {
        int mt = e / 9, nt = e - mt * 9;
        const unsigned short* arow = xw + (128 + mt * 16 + l15) * 120;
        const unsigned short* b0 = WQT + nt * 4 * 512 + ln * 8;
        f32x4 acc = {0.f,0.f,0.f,0.f};
        #pragma unroll
        for (int kk = 0; kk < 4; ++kk)
            acc = MFMA(*(const s16x8*)(arow + kk * 32 + qd * 8),
                       *(const s16x8*)(b0 + kk * 512), acc);
        int c = nt * 16 + l15;
        int hh = (c * 171) >> 12, rel = c - hh * 24;
        float bias = (rel < 20) ? qkv_b[hh * 20 + rel] * 0.22360679774997896f : 0.f;
        #pragma unroll
        for (int reg = 0; reg < 4; ++reg)
            qp[(mt * 16 + qd * 4 + reg) * 144 + c] = f2bf(acc[reg] + bias);
    }
    __syncthreads();

    // ---------------- attention: 3 (head, qtile) jobs per wave, no barriers ----------------
    const int qt = wv & 3, hp = wv >> 2;
    const int q_l = qt * 16 + l15;
    const int gq = grp_s[q_l];
    unsigned long long mbits = 0ull;
    #pragma unroll
    for (int t = 0; t < 12; ++t)
        #pragma unroll
        for (int r = 0; r < 4; ++r) {
            int tok = t * 16 + qd * 4 + r;
            if (gq != grp_s[tok & 63]) mbits |= (1ull << (t * 4 + r));
        }
    const int srcA = (((qd * 2) & 3) << 4) | l15;
    const int srcB = (((qd * 2 + 1) & 3) << 4) | l15;
    const int msel = qd >> 1;

    f32x4 pacc[8];
    #pragma unroll
    for (int i = 0; i < 8; ++i) { f32x4 z = {0.f,0.f,0.f,0.f}; pacc[i] = z; }

    for (int jj = 0; jj < 3; ++jj) {
        const int h = hp + 2 * jj;

        // rpb + shift mask (L2-resident loads, overlap the MFMAs)
        const float* rbase = RPB + ((size_t)(h * 192 + qd * 4)) * 64 + q_l;
        float vals[48];
        #pragma unroll
        for (int t = 0; t < 12; ++t)
            #pragma unroll
            for (int r = 0; r < 4; ++r)
                vals[t * 4 + r] = rbase[(t * 16 + r) * 64]
                                + (((mbits >> (t * 4 + r)) & 1ull) ? -100.f : 0.f);

        // Q B-frag: qd==3 quarter is synthesized zero
        s16x8 zf = {0,0,0,0,0,0,0,0};
        int koff = (qd == 3) ? 0 : qd * 8;
        s16x8 bQl = *(const s16x8*)(qp + q_l * 144 + h * 24 + koff);
        s16x8 bQ = (qd == 3) ? zf : bQl;

        // S^T = K * Q^T over dense K (2 x b64 per A-frag, 8B-aligned)
        f32x4 sc[12];
        #pragma unroll
        for (int t = 0; t < 12; ++t) {
            const unsigned short* kp = kd + (t * 16 + l15) * 120 + h * 20 + qd * 8;
            union { s16x8 v8; s16x4 v4[2]; } ak;
            ak.v4[0] = *(const s16x4*)(kp);
            ak.v4[1] = *(const s16x4*)(kp + 4);
            f32x4 z = {0.f,0.f,0.f,0.f};
            sc[t] = MFMA(ak.v8, bQ, z);
        }

        float m = -1e30f;
        #pragma unroll
        for (int t = 0; t < 12; ++t)
            #pragma unroll
            for (int r = 0; r < 4; ++r) {
                float v = vals[t * 4 + r] + sc[t][r];
                vals[t * 4 + r] = v; m = fmaxf(m, v);
            }
        m = fmaxf(m, __shfl_xor(m, 16));
        m = fmaxf(m, __shfl_xor(m, 32));
        float s = 0.f;
        #pragma unroll
        for (int i = 0; i < 48; ++i) { float ev = __expf(vals[i] - m); vals[i] = ev; s += ev; }
        s += __shfl_xor(s, 16);
        s += __shfl_xor(s, 32);
        float inv = 1.0f / s;

        unsigned int plo[12], phi[12];
        #pragma unroll
        for (int t = 0; t < 12; ++t) {
            plo[t] = pk2(vals[t * 4 + 0] * inv, vals[t * 4 + 1] * inv);
            phi[t] = pk2(vals[t * 4 + 2] * inv, vals[t * 4 + 3] * inv);
        }

        // PV: O^T = V^T * P^T  (A rows h*20 + d_rel; d_rel>=20 garbage killed by PJF zeros)
        f32x4 o0 = {0.f,0.f,0.f,0.f}, o1 = {0.f,0.f,0.f,0.f};
        #pragma unroll
        for (int kk = 0; kk < 6; ++kk) {
            unsigned int a0 = __shfl(plo[2 * kk],     srcA);
            unsigned int a1 = __shfl(plo[2 * kk + 1], srcA);
            unsigned int b0 = __shfl(phi[2 * kk],     srcA);
            unsigned int b1 = __shfl(phi[2 * kk + 1], srcA);
            unsigned int c0 = __shfl(plo[2 * kk],     srcB);
            unsigned int c1 = __shfl(plo[2 * kk + 1], srcB);
            unsigned int d0 = __shfl(phi[2 * kk],     srcB);
            unsigned int d1 = __shfl(phi[2 * kk + 1], srcB);
            union { s16x8 v; unsigned int u[4]; } bf;
            bf.u[0] = msel ? a1 : a0;
            bf.u[1] = msel ? b1 : b0;
            bf.u[2] = msel ? c1 : c0;
            bf.u[3] = msel ? d1 : d0;
            s16x8 aV0 = *(const s16x8*)(vt + (h * 20 + l15) * 200 + kk * 32 + qd * 8);
            s16x8 aV1 = *(const s16x8*)(vt + (h * 20 + 16 + l15) * 200 + kk * 32 + qd * 8);
            o0 = MFMA(aV0, bf.v, o0);
            o1 = MFMA(aV1, bf.v, o1);
        }

        // proj: x1^T += PW_h * O^T_h
        {
            unsigned int ol0 = pk2(o0[0], o0[1]), oh0 = pk2(o0[2], o0[3]);
            unsigned int ol1 = pk2(o1[0], o1[1]), oh1 = pk2(o1[2], o1[3]);
            unsigned int w0a = __shfl(ol0, srcA), w0b = __shfl(ol1, srcA);
            unsigned int w1a = __shfl(oh0, srcA), w1b = __shfl(oh1, srcA);
            unsigned int w2a = __shfl(ol0, srcB), w2b = __shfl(ol1, srcB);
            unsigned int w3a = __shfl(oh0, srcB), w3b = __shfl(oh1, srcB);
            union { s16x8 v; unsigned int u[4]; } bo;
            bo.u[0] = msel ? w0b : w0a;
            bo.u[1] = msel ? w1b : w1a;
            bo.u[2] = msel ? w2b : w2a;
            bo.u[3] = msel ? w3b : w3a;
            #pragma unroll
            for (int ct = 0; ct < 8; ++ct) {
                s16x8 aP = *(const s16x8*)(PJF + (h * 8 + ct) * 512 + ln * 8);
                pacc[ct] = MFMA(aP, bo.v, pacc[ct]);
            }
        }
    }
    __syncthreads();   // all attention reads of kd/xw done before overlay

    // ---------------- epilogue: pair-reduce proj partials, blend, scatter ----------------
    {
        float* xo = (float*)(smem + ((wv < 4) ? 0u : 46096u));  // [64][129] fp32 overlays
        #pragma unroll
        for (int ct = 0; ct < 8; ++ct)
            #pragma unroll
            for (int reg = 0; reg < 4; ++reg) {
                int c = ct * 16 + qd * 4 + reg;
                if (c < 120) xo[q_l * 129 + c] = pacc[ct][reg];
            }
    }
    __syncthreads();

    const float* x1p = (const float*)smem;
    const float* x2p = (const float*)(smem + 46096);
    for (int e = tid; e < 64 * 121; e += NT) {
        int r = e / 121, c = e - r * 121;
        int ii = r >> 3, jj = r & 7;
        int y0 = (wh * 8 + ii + 4) & 255;
        int x0 = (ww * 8 + jj + 4) & 255;
        float p = pred_s[r];
        float val;
        if (c < 120)
            val = (p != 0.f) ? (x1p[r * 129 + c] + x2p[r * 129 + c] + proj_b[c])
                             : quary1[(size_t)widx * 7680 + (size_t)r * 120 + c];
        else
            val = p;
        out[((size_t)(y0 * 256 + x0)) * 121 + c] = val;
    }
}

extern "C" void kernel_launch(void* const* d_in, const int* in_sizes, int n_in,
                              void* d_out, int out_size, void* d_ws, size_t ws_size,
                              hipStream_t stream) {
    const float* x        = (const float*)d_in[0];
    const float* quary0   = (const float*)d_in[1];
    const float* quary1   = (const float*)d_in[2];
    const float* qkv_w    = (const float*)d_in[3];
    const float* qkv_b    = (const float*)d_in[4];
    const float* proj_b   = (const float*)d_in[6];
    const float* proj_w   = (const float*)d_in[5];
    const float* rpb      = (const float*)d_in[7];
    const float* pm_w     = (const float*)d_in[8];
    const float* pm_b     = (const float*)d_in[9];
    const int*   rel_idx  = (const int*)d_in[11];
    float* out = (float*)d_out;
    unsigned char* wsb = (unsigned char*)d_ws;

    prep<<<128, 512, 0, stream>>>(qkv_w, proj_w, rpb, rel_idx, wsb);
    swin_mfma<<<1024, NT, 0, stream>>>(x, quary0, quary1, qkv_b, proj_b,
                                       pm_w, pm_b, wsb, out);
}